// Round 1
// 503.659 us; speedup vs baseline: 1.2160x; 1.2160x over previous
//
#include <hip/hip_runtime.h>
#include <hip/hip_bf16.h>

// Problem constants (B,T,D,H,KV,HD,RD from reference)
static constexpr int B_  = 2;
static constexpr int T_  = 2048;
static constexpr int D_  = 2048;
static constexpr int H_  = 16;
static constexpr int KV_ = 4;
static constexpr int HD_ = 128;
static constexpr int RD_ = 64;
static constexpr int BT_ = B_ * T_;           // 4096
static constexpr float SCALE_ = 0.08838834764831845f; // 1/sqrt(128)

typedef __attribute__((ext_vector_type(8))) short bf16x8;
typedef __attribute__((ext_vector_type(8))) unsigned short u16x8;
typedef __attribute__((ext_vector_type(4))) float f32x4;

#define COMPILER_BARRIER() __asm__ __volatile__("" ::: "memory")

// f32 -> bf16 (RNE) raw bits
__device__ __forceinline__ unsigned short f2bu(float f) {
  unsigned x = __float_as_uint(f);
  unsigned r = (x + 0x7fffu + ((x >> 16) & 1u)) >> 16;
  return (unsigned short)r;
}

// ---------------- f32 -> bf16 elementwise (n divisible by 1024) ----------------
__global__ __launch_bounds__(256) void cvt_bf16(const float* __restrict__ in,
                                                unsigned short* __restrict__ out) {
  const size_t i = ((size_t)blockIdx.x * 256 + threadIdx.x) * 4;
  const float4 f = *(const float4*)(in + i);
  ushort4 o;
  o.x = f2bu(f.x); o.y = f2bu(f.y); o.z = f2bu(f.z); o.w = f2bu(f.w);
  *(ushort4*)(out + i) = o;
}

// ---------------- transpose + convert: in f32 [R,C] -> out bf16 [C,R] ----------------
__global__ __launch_bounds__(256) void t32(const float* __restrict__ in,
                                           unsigned short* __restrict__ out,
                                           int R, int C) {
  __shared__ unsigned short tile[32][36];
  const int r0 = blockIdx.x * 32;
  const int c0 = blockIdx.y * 32;
  const int tid = threadIdx.x;
  {
    const int r = tid >> 3;
    const int c = (tid & 7) * 4;
    const float4 f = *(const float4*)(in + (size_t)(r0 + r) * C + c0 + c);
    ushort4 w;
    w.x = f2bu(f.x); w.y = f2bu(f.y); w.z = f2bu(f.z); w.w = f2bu(f.w);
    *(ushort4*)&tile[r][c] = w;
  }
  __syncthreads();
  {
    const int c = tid >> 3;
    const int r = (tid & 7) * 4;
    ushort4 o;
    o.x = tile[r + 0][c];
    o.y = tile[r + 1][c];
    o.z = tile[r + 2][c];
    o.w = tile[r + 3][c];
    *(ushort4*)(out + (size_t)(c0 + c) * R + r0 + r) = o;
  }
}

// ---------------- bf16 MFMA GEMM: C[M,N] = A[M,K] @ Bt[N,K]^T ----------------
template <int REMAP>
__global__ __launch_bounds__(256) void gemm_bf16(const unsigned short* __restrict__ A,
                                                 const unsigned short* __restrict__ Bt,
                                                 float* __restrict__ C,
                                                 int M, int N, int K) {
  __shared__ unsigned short As[128][40];
  __shared__ unsigned short Bs[128][40];
  const int tid = threadIdx.x;
  const int lane = tid & 63;
  const int wave = tid >> 6;
  const int n16 = lane & 15;
  const int quad = lane >> 4;
  const int bm = blockIdx.y * 128;
  const int bn = blockIdx.x * 128;
  const int wm = (wave & 1) * 64;
  const int wn = (wave >> 1) * 64;

  const int srow = tid >> 1;
  const int scol = (tid & 1) * 16;

  f32x4 acc[4][4];
#pragma unroll
  for (int mi = 0; mi < 4; ++mi)
#pragma unroll
    for (int ni = 0; ni < 4; ++ni) acc[mi][ni] = (f32x4){0.f, 0.f, 0.f, 0.f};

  const unsigned short* ag = A + (size_t)(bm + srow) * K + scol;
  const unsigned short* bg = Bt + (size_t)(bn + srow) * K + scol;

  for (int k0 = 0; k0 < K; k0 += 32) {
    *(u16x8*)&As[srow][scol]     = *(const u16x8*)(ag + k0);
    *(u16x8*)&As[srow][scol + 8] = *(const u16x8*)(ag + k0 + 8);
    *(u16x8*)&Bs[srow][scol]     = *(const u16x8*)(bg + k0);
    *(u16x8*)&Bs[srow][scol + 8] = *(const u16x8*)(bg + k0 + 8);
    __syncthreads();

    bf16x8 af[4], bf[4];
#pragma unroll
    for (int i = 0; i < 4; ++i) {
      af[i] = *(const bf16x8*)&As[wm + i * 16 + n16][quad * 8];
      bf[i] = *(const bf16x8*)&Bs[wn + i * 16 + n16][quad * 8];
    }
#pragma unroll
    for (int mi = 0; mi < 4; ++mi)
#pragma unroll
      for (int ni = 0; ni < 4; ++ni)
        acc[mi][ni] = __builtin_amdgcn_mfma_f32_16x16x32_bf16(af[mi], bf[ni], acc[mi][ni], 0, 0, 0);
    __syncthreads();
  }

#pragma unroll
  for (int mi = 0; mi < 4; ++mi) {
#pragma unroll
    for (int r = 0; r < 4; ++r) {
      const int row = bm + wm + mi * 16 + quad * 4 + r;
#pragma unroll
      for (int ni = 0; ni < 4; ++ni) {
        const int col = bn + wn + ni * 16 + n16;
        const float v = acc[mi][ni][r];
        if (REMAP == 0) {
          C[(size_t)row * N + col] = v;
        } else {
          const int b = row >> 11, t = row & (T_ - 1);
          const int part = col >> 9;
          const int kv = (col >> 7) & 3;
          const int hd = col & 127;
          C[(size_t)part * (B_ * KV_ * T_ * HD_) +
            (((size_t)(b * KV_ + kv) * T_) + t) * HD_ + hd] = v;
        }
      }
    }
  }
}

// ---------------- RoPE Q in place (f32 [BT, H*HD]) ----------------
__global__ __launch_bounds__(256) void rope_q(float* __restrict__ Q,
                                              const float* __restrict__ cosb,
                                              const float* __restrict__ sinb) {
  const int bt = blockIdx.x;
  const int t = bt % T_;
  const int tid = threadIdx.x;
  for (int i = tid; i < H_ * (RD_ / 2); i += 256) {
    const int h = i >> 5;
    const int p = i & 31;
    const float c = cosb[t * 32 + p];
    const float s = sinb[t * 32 + p];
    const size_t base = (size_t)bt * (H_ * HD_) + h * HD_ + 2 * p;
    const float e = Q[base], o = Q[base + 1];
    Q[base]     = e * c - o * s;
    Q[base + 1] = e * s + o * c;
  }
}

// ---------------- RoPE K in place (f32 [B,KV,T,HD]) + bf16 mirror ----------------
__global__ __launch_bounds__(256) void rope_k(float* __restrict__ kout,
                                              const float* __restrict__ cosb,
                                              const float* __restrict__ sinb,
                                              unsigned short* __restrict__ Kbf) {
  const int bt = blockIdx.x;
  const int t = bt % T_;
  const int b = bt / T_;
  const int tid = threadIdx.x;
  for (int i = tid; i < KV_ * (HD_ / 2); i += 256) {
    const int kv = i >> 6;
    const int p = i & 63;
    const size_t idx = (((size_t)(b * KV_ + kv) * T_) + t) * HD_ + 2 * p;
    float e = kout[idx], o = kout[idx + 1];
    if (p < 32) {
      const float c = cosb[t * 32 + p];
      const float s = sinb[t * 32 + p];
      const float re = e * c - o * s;
      const float ro = e * s + o * c;
      e = re; o = ro;
      kout[idx]     = e;
      kout[idx + 1] = o;
    }
    Kbf[idx]     = f2bu(e);
    Kbf[idx + 1] = f2bu(o);
  }
}

// ---------------- V transpose: vout f32 [G,T,HD] -> VbfT bf16 [G,HD,T] ----------------
__global__ __launch_bounds__(256) void v_transpose(const float* __restrict__ vin,
                                                   unsigned short* __restrict__ vt) {
  __shared__ unsigned int tile[32][17];
  const int tid = threadIdx.x;
  const int k0 = blockIdx.x * 32;
  const int d0 = blockIdx.y * 32;
  const int g  = blockIdx.z;
  const float* src = vin + ((size_t)g * T_ + k0) * HD_ + d0;

  {
    const int kr = tid >> 3;
    const int d2 = (tid & 7) * 2;
#pragma unroll
    for (int c = 0; c < 2; ++c) {
      const float2 f = *(const float2*)(src + (size_t)kr * HD_ + (d2 + c) * 2);
      tile[kr][d2 + c] = (unsigned)f2bu(f.x) | ((unsigned)f2bu(f.y) << 16);
    }
  }
  __syncthreads();
  {
    const int dr = tid >> 3;
    const int kc = (tid & 7) * 4;
    const int hi = dr >> 1;
    const int sh = (dr & 1) * 16;
    ushort4 o;
    o.x = (unsigned short)(tile[kc + 0][hi] >> sh);
    o.y = (unsigned short)(tile[kc + 1][hi] >> sh);
    o.z = (unsigned short)(tile[kc + 2][hi] >> sh);
    o.w = (unsigned short)(tile[kc + 3][hi] >> sh);
    *(ushort4*)(vt + ((size_t)g * HD_ + d0 + dr) * T_ + k0 + kc) = o;
  }
}

// ---------------- flash attention v2: 8 waves/block = 4 heads (same KV group) x 2 row-groups ----------------
// Block = one (q-tile, b, kv-head). All 8 waves share K/V chunks staged once in LDS
// (reg-staged, loads issued before compute so L2/HBM latency hides under MFMA+softmax).
// K tile [32][128] bf16 XOR-swizzled (row&7)<<4 : ds_read_b128 16-way conflict -> 2-way.
// V tile [128][32] bf16 XOR-swizzled (d&3)<<4   : 8-way -> 4-way.
// Per-wave softmax math identical to the verified 1-wave kernel (G fixed per wave).
__global__ __launch_bounds__(512, 4) void attn_flash(const float* __restrict__ Q,
                                                     const unsigned short* __restrict__ Kbf,
                                                     const unsigned short* __restrict__ VbfT,
                                                     unsigned short* __restrict__ O) {
  __shared__ __align__(16) unsigned short Ks[32 * 128];  // [key][d], swizzled
  __shared__ __align__(16) unsigned short Vs[128 * 32];  // [d][key], swizzled
  __shared__ float Sl[8][16][33];
  __shared__ float mA[8][16];

  const int tid = threadIdx.x;
  const int wave = tid >> 6;
  const int lane = tid & 63;
  const int n16 = lane & 15;
  const int quad = lane >> 4;
  const int hw = wave & 3;          // head within kv group
  const int G = wave >> 2;          // 16-row group within the 32-row q tile
  const int qt = (T_ / 32 - 1) - blockIdx.x;    // heavy tiles dispatched first
  const int q0 = qt * 32;
  const int bkv = blockIdx.y;
  const int b = bkv >> 2;
  const int kvh = bkv & 3;
  const int h = kvh * 4 + hw;

  const unsigned short* ksrc = Kbf + ((size_t)(b * KV_ + kvh)) * T_ * HD_;
  const unsigned short* vtsrc = VbfT + ((size_t)(b * KV_ + kvh)) * HD_ * T_;

  // staging decomposition: 512 threads x 16B = one 8KB tile per vector op
  const int krow = tid >> 4;            // 0..31  (key)
  const int kcol = (tid & 15) * 8;      // elem within 128-d row
  const int kdst = (krow * 128 + kcol) ^ ((krow & 7) << 3);
  const int vrow = tid >> 2;            // 0..127 (d)
  const int vcol = (tid & 3) * 8;       // key elem within 32-key row
  const int vdst = (vrow * 32 + vcol) ^ ((vrow & 3) << 3);

  // Q A-frags for this wave's 16-row group (scale folded in)
  bf16x8 qf[4];
  {
    const float* qbase = Q + ((size_t)(b * T_ + q0 + G * 16 + n16)) * (H_ * HD_) + h * HD_ + quad * 8;
#pragma unroll
    for (int s = 0; s < 4; ++s) {
      union { bf16x8 v; unsigned short u[8]; } qk;
#pragma unroll
      for (int j = 0; j < 8; ++j) qk.u[j] = f2bu(qbase[s * 32 + j] * SCALE_);
      qf[s] = qk.v;
    }
  }

  float mold[4];
#pragma unroll
  for (int r = 0; r < 4; ++r) mold[r] = -1e30f;
  float moldA = -1e30f;
  float lrow = 0.f;

  f32x4 oacc[8];
#pragma unroll
  for (int t = 0; t < 8; ++t) oacc[t] = (f32x4){0.f, 0.f, 0.f, 0.f};

  // stage chunk 0
  {
    const u16x8 k0 = *(const u16x8*)(ksrc + (size_t)krow * HD_ + kcol);
    const u16x8 v0 = *(const u16x8*)(vtsrc + (size_t)vrow * T_ + vcol);
    *(u16x8*)&Ks[kdst] = k0;
    *(u16x8*)&Vs[vdst] = v0;
  }
  __syncthreads();

  for (int c = 0; c <= qt; ++c) {
    const int kc = c * 32;

    // T14 async-STAGE split: issue next chunk's global loads now; ds_write after barrier
    u16x8 knxt, vnxt;
    if (c < qt) {
      knxt = *(const u16x8*)(ksrc + (size_t)(kc + 32 + krow) * HD_ + kcol);
      vnxt = *(const u16x8*)(vtsrc + (size_t)vrow * T_ + (kc + 32) + vcol);
    }
    COMPILER_BARRIER();   // keep prefetch loads issued before the compute phase

    // ---- QK^T from swizzled LDS ----
    f32x4 acc0 = (f32x4){0.f, 0.f, 0.f, 0.f};
    f32x4 acc1 = (f32x4){0.f, 0.f, 0.f, 0.f};
#pragma unroll
    for (int s = 0; s < 4; ++s) {
      const bf16x8 kf0 = *(const bf16x8*)&Ks[(n16 * 128 + quad * 8 + s * 32) ^ ((n16 & 7) << 3)];
      const bf16x8 kf1 = *(const bf16x8*)&Ks[((16 + n16) * 128 + quad * 8 + s * 32) ^ ((n16 & 7) << 3)];
      acc0 = __builtin_amdgcn_mfma_f32_16x16x32_bf16(qf[s], kf0, acc0, 0, 0, 0);
      acc1 = __builtin_amdgcn_mfma_f32_16x16x32_bf16(qf[s], kf1, acc1, 0, 0, 0);
    }

    // ---- mask, stash S (C-layout), shuffle row-max, m/alpha update ----
    float alphaC[4];
    {
      f32x4 mnewv;
#pragma unroll
      for (int r = 0; r < 4; ++r) {
        const int qrow = q0 + G * 16 + quad * 4 + r;
        const float s0 = (kc + n16 <= qrow) ? acc0[r] : -1e30f;
        const float s1 = (kc + 16 + n16 <= qrow) ? acc1[r] : -1e30f;
        Sl[wave][quad * 4 + r][n16] = s0;
        Sl[wave][quad * 4 + r][16 + n16] = s1;
        float mm = fmaxf(s0, s1);
        mm = fmaxf(mm, __shfl_xor(mm, 1));
        mm = fmaxf(mm, __shfl_xor(mm, 2));
        mm = fmaxf(mm, __shfl_xor(mm, 4));
        mm = fmaxf(mm, __shfl_xor(mm, 8));
        const float mn = fmaxf(mold[r], mm);
        mnewv[r] = mn;
        alphaC[r] = __expf(mold[r] - mn);
        mold[r] = mn;
      }
      if (n16 == 0) *(f32x4*)&mA[wave][quad * 4] = mnewv;
    }
    COMPILER_BARRIER();   // same-wave DS in-order: mA write before mA read below

    // ---- P = exp(S - m) in A-layout; shuffle row-sum; l update ----
    union { bf16x8 v; unsigned short u[8]; } pk;
    {
      const float mAl = mA[wave][n16];
      const float alphaA = __expf(moldA - mAl);
      moldA = mAl;
      float lsum = 0.f;
      const float* srow = &Sl[wave][n16][quad * 8];
#pragma unroll
      for (int j = 0; j < 8; ++j) {
        const float p = __expf(srow[j] - mAl);
        lsum += p;
        pk.u[j] = f2bu(p);
      }
      lsum += __shfl_xor(lsum, 16);
      lsum += __shfl_xor(lsum, 32);
      lrow = alphaA * lrow + lsum;
    }

    // ---- rescale O, PV from swizzled LDS ----
#pragma unroll
    for (int t = 0; t < 8; ++t) {
      const bf16x8 vf = *(const bf16x8*)&Vs[((t * 16 + n16) * 32 + quad * 8) ^ ((n16 & 3) << 3)];
      oacc[t][0] *= alphaC[0]; oacc[t][1] *= alphaC[1];
      oacc[t][2] *= alphaC[2]; oacc[t][3] *= alphaC[3];
      oacc[t] = __builtin_amdgcn_mfma_f32_16x16x32_bf16(pk.v, vf, oacc[t], 0, 0, 0);
    }

    __syncthreads();      // all waves done reading this chunk's K/V tiles
    if (c < qt) {
      *(u16x8*)&Ks[kdst] = knxt;   // vmcnt wait for prefetch lands here (post-compute)
      *(u16x8*)&Vs[vdst] = vnxt;
    }
    __syncthreads();      // next chunk's tiles visible to all waves
  }

  // ---- epilogue: l -> C-layout via LDS, normalize, store bf16 ----
  if (quad == 0) mA[wave][n16] = lrow;
  COMPILER_BARRIER();
  {
    const f32x4 lC = *(const f32x4*)&mA[wave][quad * 4];
    unsigned short* obase = O + ((size_t)(b * T_ + q0 + G * 16)) * (H_ * HD_) + h * HD_;
#pragma unroll
    for (int r = 0; r < 4; ++r) {
      const float linv = 1.0f / lC[r];
#pragma unroll
      for (int t = 0; t < 8; ++t) {
        obase[(size_t)(quad * 4 + r) * (H_ * HD_) + t * 16 + n16] = f2bu(oacc[t][r] * linv);
      }
    }
  }
}

extern "C" void kernel_launch(void* const* d_in, const int* in_sizes, int n_in,
                              void* d_out, int out_size, void* d_ws, size_t ws_size,
                              hipStream_t stream) {
  const float* x  = (const float*)d_in[0];
  const float* fc = (const float*)d_in[1];
  const float* fs = (const float*)d_in[2];
  const float* Wq = (const float*)d_in[3];
  const float* Wk = (const float*)d_in[4];
  const float* Wv = (const float*)d_in[5];
  const float* Wo = (const float*)d_in[6];

  // Outputs (f32), concatenated: y | present_k | present_v
  float* yout = (float*)d_out;                          // [B,T,D]
  float* kout = yout + (size_t)B_ * T_ * D_;            // [B,KV,T,HD]
  float* vout = kout + (size_t)B_ * KV_ * T_ * HD_;     // [B,KV,T,HD]
  float* Qb = yout;                                     // f32 Q staging in yout region

  // workspace (bf16, 46.1 MB): xb/Abf (aliased) | Wqt | Wkvt | Wot | Kbf | VbfT
  unsigned short* xb   = (unsigned short*)d_ws;                    // [BT, D]
  unsigned short* Abf  = xb;                                       // alias: xb dead after projections
  unsigned short* Wqt  = xb   + (size_t)BT_ * D_;                  // [2048, 2048]
  unsigned short* Wkvt = Wqt  + (size_t)D_ * D_;                   // [1024, 2048]
  unsigned short* Wot  = Wkvt + (size_t)1024 * D_;                 // [2048, 2048]
  unsigned short* Kbf  = Wot  + (size_t)D_ * D_;                   // [B,KV,T,HD]
  unsigned short* VbfT = Kbf  + (size_t)B_ * KV_ * T_ * HD_;       // [B*KV, HD, T]

  dim3 blk(256);

  // input conversions
  cvt_bf16<<<dim3((BT_ * D_) / 1024), blk, 0, stream>>>(x, xb);
  t32<<<dim3(D_ / 32, D_ / 32), blk, 0, stream>>>(Wq, Wqt, D_, D_);
  t32<<<dim3(D_ / 32, 512 / 32), blk, 0, stream>>>(Wk, Wkvt, D_, 512);
  t32<<<dim3(D_ / 32, 512 / 32), blk, 0, stream>>>(Wv, Wkvt + (size_t)512 * D_, D_, 512);
  t32<<<dim3(D_ / 32, D_ / 32), blk, 0, stream>>>(Wo, Wot, D_, D_);

  // projections (bf16 MFMA, f32 out)
  gemm_bf16<0><<<dim3(D_ / 128, BT_ / 128), blk, 0, stream>>>(xb, Wqt, Qb, BT_, D_, D_);
  gemm_bf16<1><<<dim3(1024 / 128, BT_ / 128), blk, 0, stream>>>(xb, Wkvt, kout, BT_, 1024, D_);

  // RoPE (Q and K in place) + bf16 K mirror; V^T bf16 mirror
  rope_q<<<dim3(BT_), blk, 0, stream>>>(Qb, fc, fs);
  rope_k<<<dim3(BT_), blk, 0, stream>>>(kout, fc, fs, Kbf);
  v_transpose<<<dim3(T_ / 32, HD_ / 32, B_ * KV_), blk, 0, stream>>>(vout, VbfT);

  // flash attention v2: 8 waves/block, K/V staged in swizzled LDS
  attn_flash<<<dim3(T_ / 32, B_ * KV_), dim3(512), 0, stream>>>(Qb, Kbf, VbfT, Abf);

  // output projection; overwrites Qb staging with y
  gemm_bf16<0><<<dim3(D_ / 128, BT_ / 128), blk, 0, stream>>>(Abf, Wot, yout, BT_, D_, D_);
}

// Round 2
// 462.729 us; speedup vs baseline: 1.3235x; 1.0885x over previous
//
#include <hip/hip_runtime.h>
#include <hip/hip_bf16.h>

// Problem constants (B,T,D,H,KV,HD,RD from reference)
static constexpr int B_  = 2;
static constexpr int T_  = 2048;
static constexpr int D_  = 2048;
static constexpr int H_  = 16;
static constexpr int KV_ = 4;
static constexpr int HD_ = 128;
static constexpr int RD_ = 64;
static constexpr int BT_ = B_ * T_;           // 4096
static constexpr float SCALE_ = 0.08838834764831845f; // 1/sqrt(128)

typedef __attribute__((ext_vector_type(8))) short bf16x8;
typedef __attribute__((ext_vector_type(8))) unsigned short u16x8;
typedef __attribute__((ext_vector_type(4))) float f32x4;

#define COMPILER_BARRIER() __asm__ __volatile__("" ::: "memory")

// f32 -> bf16 (RNE) raw bits
__device__ __forceinline__ unsigned short f2bu(float f) {
  unsigned x = __float_as_uint(f);
  unsigned r = (x + 0x7fffu + ((x >> 16) & 1u)) >> 16;
  return (unsigned short)r;
}

// ---------------- f32 -> bf16 elementwise (n divisible by 1024) ----------------
__global__ __launch_bounds__(256) void cvt_bf16(const float* __restrict__ in,
                                                unsigned short* __restrict__ out) {
  const size_t i = ((size_t)blockIdx.x * 256 + threadIdx.x) * 4;
  const float4 f = *(const float4*)(in + i);
  ushort4 o;
  o.x = f2bu(f.x); o.y = f2bu(f.y); o.z = f2bu(f.z); o.w = f2bu(f.w);
  *(ushort4*)(out + i) = o;
}

// ---------------- transpose + convert: in f32 [R,C] -> out bf16 [C,R] ----------------
__global__ __launch_bounds__(256) void t32(const float* __restrict__ in,
                                           unsigned short* __restrict__ out,
                                           int R, int C) {
  __shared__ unsigned short tile[32][36];
  const int r0 = blockIdx.x * 32;
  const int c0 = blockIdx.y * 32;
  const int tid = threadIdx.x;
  {
    const int r = tid >> 3;
    const int c = (tid & 7) * 4;
    const float4 f = *(const float4*)(in + (size_t)(r0 + r) * C + c0 + c);
    ushort4 w;
    w.x = f2bu(f.x); w.y = f2bu(f.y); w.z = f2bu(f.z); w.w = f2bu(f.w);
    *(ushort4*)&tile[r][c] = w;
  }
  __syncthreads();
  {
    const int c = tid >> 3;
    const int r = (tid & 7) * 4;
    ushort4 o;
    o.x = tile[r + 0][c];
    o.y = tile[r + 1][c];
    o.z = tile[r + 2][c];
    o.w = tile[r + 3][c];
    *(ushort4*)(out + (size_t)(c0 + c) * R + r0 + r) = o;
  }
}

// ---------------- bf16 MFMA GEMM: C[M,N] = A[M,K] @ Bt[N,K]^T ----------------
template <int REMAP>
__global__ __launch_bounds__(256) void gemm_bf16(const unsigned short* __restrict__ A,
                                                 const unsigned short* __restrict__ Bt,
                                                 float* __restrict__ C,
                                                 int M, int N, int K) {
  __shared__ unsigned short As[128][40];
  __shared__ unsigned short Bs[128][40];
  const int tid = threadIdx.x;
  const int lane = tid & 63;
  const int wave = tid >> 6;
  const int n16 = lane & 15;
  const int quad = lane >> 4;
  const int bm = blockIdx.y * 128;
  const int bn = blockIdx.x * 128;
  const int wm = (wave & 1) * 64;
  const int wn = (wave >> 1) * 64;

  const int srow = tid >> 1;
  const int scol = (tid & 1) * 16;

  f32x4 acc[4][4];
#pragma unroll
  for (int mi = 0; mi < 4; ++mi)
#pragma unroll
    for (int ni = 0; ni < 4; ++ni) acc[mi][ni] = (f32x4){0.f, 0.f, 0.f, 0.f};

  const unsigned short* ag = A + (size_t)(bm + srow) * K + scol;
  const unsigned short* bg = Bt + (size_t)(bn + srow) * K + scol;

  for (int k0 = 0; k0 < K; k0 += 32) {
    *(u16x8*)&As[srow][scol]     = *(const u16x8*)(ag + k0);
    *(u16x8*)&As[srow][scol + 8] = *(const u16x8*)(ag + k0 + 8);
    *(u16x8*)&Bs[srow][scol]     = *(const u16x8*)(bg + k0);
    *(u16x8*)&Bs[srow][scol + 8] = *(const u16x8*)(bg + k0 + 8);
    __syncthreads();

    bf16x8 af[4], bf[4];
#pragma unroll
    for (int i = 0; i < 4; ++i) {
      af[i] = *(const bf16x8*)&As[wm + i * 16 + n16][quad * 8];
      bf[i] = *(const bf16x8*)&Bs[wn + i * 16 + n16][quad * 8];
    }
#pragma unroll
    for (int mi = 0; mi < 4; ++mi)
#pragma unroll
      for (int ni = 0; ni < 4; ++ni)
        acc[mi][ni] = __builtin_amdgcn_mfma_f32_16x16x32_bf16(af[mi], bf[ni], acc[mi][ni], 0, 0, 0);
    __syncthreads();
  }

#pragma unroll
  for (int mi = 0; mi < 4; ++mi) {
#pragma unroll
    for (int r = 0; r < 4; ++r) {
      const int row = bm + wm + mi * 16 + quad * 4 + r;
#pragma unroll
      for (int ni = 0; ni < 4; ++ni) {
        const int col = bn + wn + ni * 16 + n16;
        const float v = acc[mi][ni][r];
        if (REMAP == 0) {
          C[(size_t)row * N + col] = v;
        } else {
          const int b = row >> 11, t = row & (T_ - 1);
          const int part = col >> 9;
          const int kv = (col >> 7) & 3;
          const int hd = col & 127;
          C[(size_t)part * (B_ * KV_ * T_ * HD_) +
            (((size_t)(b * KV_ + kv) * T_) + t) * HD_ + hd] = v;
        }
      }
    }
  }
}

// ---------------- RoPE Q in place (f32 [BT, H*HD]) ----------------
__global__ __launch_bounds__(256) void rope_q(float* __restrict__ Q,
                                              const float* __restrict__ cosb,
                                              const float* __restrict__ sinb) {
  const int bt = blockIdx.x;
  const int t = bt % T_;
  const int tid = threadIdx.x;
  for (int i = tid; i < H_ * (RD_ / 2); i += 256) {
    const int h = i >> 5;
    const int p = i & 31;
    const float c = cosb[t * 32 + p];
    const float s = sinb[t * 32 + p];
    const size_t base = (size_t)bt * (H_ * HD_) + h * HD_ + 2 * p;
    const float e = Q[base], o = Q[base + 1];
    Q[base]     = e * c - o * s;
    Q[base + 1] = e * s + o * c;
  }
}

// ---------------- RoPE K in place (f32 [B,KV,T,HD]) + bf16 mirror ----------------
__global__ __launch_bounds__(256) void rope_k(float* __restrict__ kout,
                                              const float* __restrict__ cosb,
                                              const float* __restrict__ sinb,
                                              unsigned short* __restrict__ Kbf) {
  const int bt = blockIdx.x;
  const int t = bt % T_;
  const int b = bt / T_;
  const int tid = threadIdx.x;
  for (int i = tid; i < KV_ * (HD_ / 2); i += 256) {
    const int kv = i >> 6;
    const int p = i & 63;
    const size_t idx = (((size_t)(b * KV_ + kv) * T_) + t) * HD_ + 2 * p;
    float e = kout[idx], o = kout[idx + 1];
    if (p < 32) {
      const float c = cosb[t * 32 + p];
      const float s = sinb[t * 32 + p];
      const float re = e * c - o * s;
      const float ro = e * s + o * c;
      e = re; o = ro;
      kout[idx]     = e;
      kout[idx + 1] = o;
    }
    Kbf[idx]     = f2bu(e);
    Kbf[idx + 1] = f2bu(o);
  }
}

// ---------------- V transpose: vout f32 [G,T,HD] -> VbfT bf16 [G,HD,T] ----------------
__global__ __launch_bounds__(256) void v_transpose(const float* __restrict__ vin,
                                                   unsigned short* __restrict__ vt) {
  __shared__ unsigned int tile[32][17];
  const int tid = threadIdx.x;
  const int k0 = blockIdx.x * 32;
  const int d0 = blockIdx.y * 32;
  const int g  = blockIdx.z;
  const float* src = vin + ((size_t)g * T_ + k0) * HD_ + d0;

  {
    const int kr = tid >> 3;
    const int d2 = (tid & 7) * 2;
#pragma unroll
    for (int c = 0; c < 2; ++c) {
      const float2 f = *(const float2*)(src + (size_t)kr * HD_ + (d2 + c) * 2);
      tile[kr][d2 + c] = (unsigned)f2bu(f.x) | ((unsigned)f2bu(f.y) << 16);
    }
  }
  __syncthreads();
  {
    const int dr = tid >> 3;
    const int kc = (tid & 7) * 4;
    const int hi = dr >> 1;
    const int sh = (dr & 1) * 16;
    ushort4 o;
    o.x = (unsigned short)(tile[kc + 0][hi] >> sh);
    o.y = (unsigned short)(tile[kc + 1][hi] >> sh);
    o.z = (unsigned short)(tile[kc + 2][hi] >> sh);
    o.w = (unsigned short)(tile[kc + 3][hi] >> sh);
    *(ushort4*)(vt + ((size_t)g * HD_ + d0 + dr) * T_ + k0 + kc) = o;
  }
}

// ---------------- flash attention v3: 4 waves/block = 4 heads (same KV group), 16-row q-tile ----------------
// Block = one (16-row q-tile, b, kv-head); 1024 blocks -> ~4 co-resident/CU (fixes the
// 1-block/CU starvation seen in v2: occupancy 22%). K/V staged once per block in swizzled
// LDS (reg-staged prefetch, writes after barrier). Softmax runs entirely in A-layout after
// an S round-trip through LDS (stride 36 = 16B-aligned rows, conflict-free b128 reads):
// row-max needs only 2 shuffles (was 16), per-row alpha computed once and broadcast to
// C-layout via LDS (deletes 4 exp + separate C-layout max state).
__global__ __launch_bounds__(256) void attn_flash(const float* __restrict__ Q,
                                                  const unsigned short* __restrict__ Kbf,
                                                  const unsigned short* __restrict__ VbfT,
                                                  unsigned short* __restrict__ O) {
  __shared__ __align__(16) unsigned short Ks[32 * 128];  // [key][d], swizzled
  __shared__ __align__(16) unsigned short Vs[128 * 32];  // [d][key], swizzled
  __shared__ __align__(16) float Sl[4][16][36];          // raw S stash, per wave
  __shared__ __align__(16) float mAl[4][16];             // per-row alpha broadcast
  __shared__ __align__(16) float lA[4][16];              // epilogue l

  const int tid = threadIdx.x;
  const int wave = tid >> 6;        // = head within kv group
  const int lane = tid & 63;
  const int n16 = lane & 15;
  const int quad = lane >> 4;
  const int qt = (T_ / 16 - 1) - blockIdx.x;   // heavy tiles dispatched first
  const int q0 = qt * 16;
  const int bkv = blockIdx.y;
  const int b = bkv >> 2;
  const int kvh = bkv & 3;
  const int h = kvh * 4 + wave;
  const int nchunks = (q0 + 16 + 31) >> 5;

  const unsigned short* ksrc = Kbf + ((size_t)(b * KV_ + kvh)) * T_ * HD_;
  const unsigned short* vtsrc = VbfT + ((size_t)(b * KV_ + kvh)) * HD_ * T_;

  // staging decomposition: 256 threads x 16B x 2 ops per tile
  const int krow = tid >> 4;            // 0..15 (+16 for second op)
  const int kcol = (tid & 15) * 8;
  const int kdst0 = (krow * 128 + kcol) ^ ((krow & 7) << 3);
  const int kdst1 = ((krow + 16) * 128 + kcol) ^ ((krow & 7) << 3);
  const int vrow = tid >> 2;            // 0..63 (+64 for second op)
  const int vcol = (tid & 3) * 8;
  const int vdst0 = (vrow * 32 + vcol) ^ ((vrow & 3) << 3);
  const int vdst1 = ((vrow + 64) * 32 + vcol) ^ ((vrow & 3) << 3);

  // Q A-frags (scale folded in)
  bf16x8 qf[4];
  {
    const float* qbase = Q + ((size_t)(b * T_ + q0 + n16)) * (H_ * HD_) + h * HD_ + quad * 8;
#pragma unroll
    for (int s = 0; s < 4; ++s) {
      union { bf16x8 v; unsigned short u[8]; } qk;
#pragma unroll
      for (int j = 0; j < 8; ++j) qk.u[j] = f2bu(qbase[s * 32 + j] * SCALE_);
      qf[s] = qk.v;
    }
  }

  float moldA = -1e30f;
  float lrow = 0.f;

  f32x4 oacc[8];
#pragma unroll
  for (int t = 0; t < 8; ++t) oacc[t] = (f32x4){0.f, 0.f, 0.f, 0.f};

  // stage chunk 0
  {
    const u16x8 ka = *(const u16x8*)(ksrc + (size_t)krow * HD_ + kcol);
    const u16x8 kb = *(const u16x8*)(ksrc + (size_t)(krow + 16) * HD_ + kcol);
    const u16x8 va = *(const u16x8*)(vtsrc + (size_t)vrow * T_ + vcol);
    const u16x8 vb = *(const u16x8*)(vtsrc + (size_t)(vrow + 64) * T_ + vcol);
    *(u16x8*)&Ks[kdst0] = ka;
    *(u16x8*)&Ks[kdst1] = kb;
    *(u16x8*)&Vs[vdst0] = va;
    *(u16x8*)&Vs[vdst1] = vb;
  }
  __syncthreads();

  for (int c = 0; c < nchunks; ++c) {
    const int kc = c * 32;
    const bool domask = (kc + 31 > q0);   // only the last chunk needs causal masking

    // T14 async-STAGE split: issue next chunk's global loads now; ds_write after barrier
    u16x8 ka, kb, va, vb;
    if (c + 1 < nchunks) {
      ka = *(const u16x8*)(ksrc + (size_t)(kc + 32 + krow) * HD_ + kcol);
      kb = *(const u16x8*)(ksrc + (size_t)(kc + 48 + krow) * HD_ + kcol);
      va = *(const u16x8*)(vtsrc + (size_t)vrow * T_ + (kc + 32) + vcol);
      vb = *(const u16x8*)(vtsrc + (size_t)(vrow + 64) * T_ + (kc + 32) + vcol);
    }
    COMPILER_BARRIER();   // keep prefetch loads issued before the compute phase

    // ---- QK^T from swizzled LDS ----
    f32x4 acc0 = (f32x4){0.f, 0.f, 0.f, 0.f};
    f32x4 acc1 = (f32x4){0.f, 0.f, 0.f, 0.f};
#pragma unroll
    for (int s = 0; s < 4; ++s) {
      const bf16x8 kf0 = *(const bf16x8*)&Ks[(n16 * 128 + quad * 8 + s * 32) ^ ((n16 & 7) << 3)];
      const bf16x8 kf1 = *(const bf16x8*)&Ks[((16 + n16) * 128 + quad * 8 + s * 32) ^ ((n16 & 7) << 3)];
      acc0 = __builtin_amdgcn_mfma_f32_16x16x32_bf16(qf[s], kf0, acc0, 0, 0, 0);
      acc1 = __builtin_amdgcn_mfma_f32_16x16x32_bf16(qf[s], kf1, acc1, 0, 0, 0);
    }

    // ---- stash raw S (C-layout write, stride 36: 2-way = free) ----
#pragma unroll
    for (int r = 0; r < 4; ++r) {
      Sl[wave][quad * 4 + r][n16] = acc0[r];
      Sl[wave][quad * 4 + r][16 + n16] = acc1[r];
    }
    COMPILER_BARRIER();   // same-wave DS in-order: writes before A-layout reads

    // ---- A-layout softmax: mask, row-max (2 shfl), alpha, P, row-sum ----
    union { bf16x8 v; unsigned short u[8]; } pk;
    {
      float s[8];
      const float* srow = &Sl[wave][n16][quad * 8];
#pragma unroll
      for (int j = 0; j < 8; ++j) s[j] = srow[j];
      if (domask) {
        const int qrow = q0 + n16;
#pragma unroll
        for (int j = 0; j < 8; ++j)
          if (kc + quad * 8 + j > qrow) s[j] = -1e30f;
      }
      float mm = fmaxf(fmaxf(fmaxf(s[0], s[1]), fmaxf(s[2], s[3])),
                       fmaxf(fmaxf(s[4], s[5]), fmaxf(s[6], s[7])));
      mm = fmaxf(mm, __shfl_xor(mm, 16));
      mm = fmaxf(mm, __shfl_xor(mm, 32));
      const float mnew = fmaxf(moldA, mm);
      const float alpha = __expf(moldA - mnew);
      moldA = mnew;
      float lsum = 0.f;
#pragma unroll
      for (int j = 0; j < 8; ++j) {
        const float p = __expf(s[j] - mnew);
        lsum += p;
        pk.u[j] = f2bu(p);
      }
      lsum += __shfl_xor(lsum, 16);
      lsum += __shfl_xor(lsum, 32);
      lrow = alpha * lrow + lsum;
      if (quad == 0) mAl[wave][n16] = alpha;
    }
    COMPILER_BARRIER();   // alpha write before C-layout read below

    // ---- rescale O by per-row alpha, PV from swizzled LDS ----
    const f32x4 av = *(const f32x4*)&mAl[wave][quad * 4];
#pragma unroll
    for (int t = 0; t < 8; ++t) {
      const bf16x8 vf = *(const bf16x8*)&Vs[((t * 16 + n16) * 32 + quad * 8) ^ ((n16 & 3) << 3)];
      oacc[t][0] *= av[0]; oacc[t][1] *= av[1];
      oacc[t][2] *= av[2]; oacc[t][3] *= av[3];
      oacc[t] = __builtin_amdgcn_mfma_f32_16x16x32_bf16(pk.v, vf, oacc[t], 0, 0, 0);
    }

    __syncthreads();      // all waves done reading this chunk's K/V tiles
    if (c + 1 < nchunks) {
      *(u16x8*)&Ks[kdst0] = ka;   // vmcnt wait for prefetch lands here (post-compute)
      *(u16x8*)&Ks[kdst1] = kb;
      *(u16x8*)&Vs[vdst0] = va;
      *(u16x8*)&Vs[vdst1] = vb;
    }
    __syncthreads();      // next chunk's tiles visible to all waves
  }

  // ---- epilogue: l -> C-layout via LDS, normalize, store bf16 ----
  if (quad == 0) lA[wave][n16] = lrow;
  COMPILER_BARRIER();
  {
    const f32x4 lC = *(const f32x4*)&lA[wave][quad * 4];
    unsigned short* obase = O + ((size_t)(b * T_ + q0)) * (H_ * HD_) + h * HD_;
#pragma unroll
    for (int r = 0; r < 4; ++r) {
      const float linv = 1.0f / lC[r];
#pragma unroll
      for (int t = 0; t < 8; ++t) {
        obase[(size_t)(quad * 4 + r) * (H_ * HD_) + t * 16 + n16] = f2bu(oacc[t][r] * linv);
      }
    }
  }
}

extern "C" void kernel_launch(void* const* d_in, const int* in_sizes, int n_in,
                              void* d_out, int out_size, void* d_ws, size_t ws_size,
                              hipStream_t stream) {
  const float* x  = (const float*)d_in[0];
  const float* fc = (const float*)d_in[1];
  const float* fs = (const float*)d_in[2];
  const float* Wq = (const float*)d_in[3];
  const float* Wk = (const float*)d_in[4];
  const float* Wv = (const float*)d_in[5];
  const float* Wo = (const float*)d_in[6];

  // Outputs (f32), concatenated: y | present_k | present_v
  float* yout = (float*)d_out;                          // [B,T,D]
  float* kout = yout + (size_t)B_ * T_ * D_;            // [B,KV,T,HD]
  float* vout = kout + (size_t)B_ * KV_ * T_ * HD_;     // [B,KV,T,HD]
  float* Qb = yout;                                     // f32 Q staging in yout region

  // workspace (bf16, 46.1 MB): xb/Abf (aliased) | Wqt | Wkvt | Wot | Kbf | VbfT
  unsigned short* xb   = (unsigned short*)d_ws;                    // [BT, D]
  unsigned short* Abf  = xb;                                       // alias: xb dead after projections
  unsigned short* Wqt  = xb   + (size_t)BT_ * D_;                  // [2048, 2048]
  unsigned short* Wkvt = Wqt  + (size_t)D_ * D_;                   // [1024, 2048]
  unsigned short* Wot  = Wkvt + (size_t)1024 * D_;                 // [2048, 2048]
  unsigned short* Kbf  = Wot  + (size_t)D_ * D_;                   // [B,KV,T,HD]
  unsigned short* VbfT = Kbf  + (size_t)B_ * KV_ * T_ * HD_;       // [B*KV, HD, T]

  dim3 blk(256);

  // input conversions
  cvt_bf16<<<dim3((BT_ * D_) / 1024), blk, 0, stream>>>(x, xb);
  t32<<<dim3(D_ / 32, D_ / 32), blk, 0, stream>>>(Wq, Wqt, D_, D_);
  t32<<<dim3(D_ / 32, 512 / 32), blk, 0, stream>>>(Wk, Wkvt, D_, 512);
  t32<<<dim3(D_ / 32, 512 / 32), blk, 0, stream>>>(Wv, Wkvt + (size_t)512 * D_, D_, 512);
  t32<<<dim3(D_ / 32, D_ / 32), blk, 0, stream>>>(Wo, Wot, D_, D_);

  // projections (bf16 MFMA, f32 out)
  gemm_bf16<0><<<dim3(D_ / 128, BT_ / 128), blk, 0, stream>>>(xb, Wqt, Qb, BT_, D_, D_);
  gemm_bf16<1><<<dim3(1024 / 128, BT_ / 128), blk, 0, stream>>>(xb, Wkvt, kout, BT_, 1024, D_);

  // RoPE (Q and K in place) + bf16 K mirror; V^T bf16 mirror
  rope_q<<<dim3(BT_), blk, 0, stream>>>(Qb, fc, fs);
  rope_k<<<dim3(BT_), blk, 0, stream>>>(kout, fc, fs, Kbf);
  v_transpose<<<dim3(T_ / 32, HD_ / 32, B_ * KV_), blk, 0, stream>>>(vout, VbfT);

  // flash attention v3: 4 waves/block, 16-row q-tiles, 1024 blocks
  attn_flash<<<dim3(T_ / 16, B_ * KV_), dim3(256), 0, stream>>>(Qb, Kbf, VbfT, Abf);

  // output projection; overwrites Qb staging with y
  gemm_bf16<0><<<dim3(D_ / 128, BT_ / 128), blk, 0, stream>>>(Abf, Wot, yout, BT_, D_, D_);
}

// Round 3
// 402.470 us; speedup vs baseline: 1.5217x; 1.1497x over previous
//
#include <hip/hip_runtime.h>
#include <hip/hip_bf16.h>

// Problem constants (B,T,D,H,KV,HD,RD from reference)
static constexpr int B_  = 2;
static constexpr int T_  = 2048;
static constexpr int D_  = 2048;
static constexpr int H_  = 16;
static constexpr int KV_ = 4;
static constexpr int HD_ = 128;
static constexpr int RD_ = 64;
static constexpr int BT_ = B_ * T_;           // 4096
static constexpr float SCALE_ = 0.08838834764831845f; // 1/sqrt(128)

typedef __attribute__((ext_vector_type(8))) short bf16x8;
typedef __attribute__((ext_vector_type(8))) unsigned short u16x8;
typedef __attribute__((ext_vector_type(4))) float f32x4;

#define COMPILER_BARRIER() __asm__ __volatile__("" ::: "memory")

// async global->LDS DMA, 16B per lane; LDS dest = wave-uniform base + lane*16
typedef const __attribute__((address_space(1))) unsigned int* as1_u32p;
typedef __attribute__((address_space(3))) unsigned int* as3_u32p;
#define GLOAD16(g, l) __builtin_amdgcn_global_load_lds((as1_u32p)(const void*)(g), (as3_u32p)(void*)(l), 16, 0, 0)

// f32 -> bf16 (RNE) raw bits
__device__ __forceinline__ unsigned short f2bu(float f) {
  unsigned x = __float_as_uint(f);
  unsigned r = (x + 0x7fffu + ((x >> 16) & 1u)) >> 16;
  return (unsigned short)r;
}

// ---------------- f32 -> bf16 elementwise (n divisible by 1024) ----------------
__global__ __launch_bounds__(256) void cvt_bf16(const float* __restrict__ in,
                                                unsigned short* __restrict__ out) {
  const size_t i = ((size_t)blockIdx.x * 256 + threadIdx.x) * 4;
  const float4 f = *(const float4*)(in + i);
  ushort4 o;
  o.x = f2bu(f.x); o.y = f2bu(f.y); o.z = f2bu(f.z); o.w = f2bu(f.w);
  *(ushort4*)(out + i) = o;
}

// ---------------- transpose + convert: in f32 [R,C] -> out bf16 [C,R] ----------------
__global__ __launch_bounds__(256) void t32(const float* __restrict__ in,
                                           unsigned short* __restrict__ out,
                                           int R, int C) {
  __shared__ unsigned short tile[32][36];
  const int r0 = blockIdx.x * 32;
  const int c0 = blockIdx.y * 32;
  const int tid = threadIdx.x;
  {
    const int r = tid >> 3;
    const int c = (tid & 7) * 4;
    const float4 f = *(const float4*)(in + (size_t)(r0 + r) * C + c0 + c);
    ushort4 w;
    w.x = f2bu(f.x); w.y = f2bu(f.y); w.z = f2bu(f.z); w.w = f2bu(f.w);
    *(ushort4*)&tile[r][c] = w;
  }
  __syncthreads();
  {
    const int c = tid >> 3;
    const int r = (tid & 7) * 4;
    ushort4 o;
    o.x = tile[r + 0][c];
    o.y = tile[r + 1][c];
    o.z = tile[r + 2][c];
    o.w = tile[r + 3][c];
    *(ushort4*)(out + (size_t)(c0 + c) * R + r0 + r) = o;
  }
}

// ---------------- bf16 MFMA GEMM (m97 structure): C[M,N] = A[M,K] @ Bt[N,K]^T ----------------
// global_load_lds width-16 staging into LINEAR [128][32] LDS tiles (no pad; DMA dest must
// be contiguous in lane order). Frag reads are b128, phase-minimal on the 64B row stride.
template <int REMAP>
__global__ __launch_bounds__(256) void gemm_bf16(const unsigned short* __restrict__ A,
                                                 const unsigned short* __restrict__ Bt,
                                                 float* __restrict__ C,
                                                 int M, int N, int K) {
  __shared__ __align__(16) unsigned short As[128 * 32];
  __shared__ __align__(16) unsigned short Bs[128 * 32];
  const int tid = threadIdx.x;
  const int lane = tid & 63;
  const int wave = tid >> 6;
  const int n16 = lane & 15;
  const int quad = lane >> 4;
  const int bm = blockIdx.y * 128;
  const int bn = blockIdx.x * 128;
  const int wm = (wave & 1) * 64;
  const int wn = (wave >> 1) * 64;

  // staging: thread tid covers LDS bytes tid*16 (rows 0..63) and 4096+tid*16 (rows 64..127)
  const int gr = tid >> 2;              // 0..63
  const int gc = (tid & 3) * 8;
  const unsigned short* agA = A  + (size_t)(bm + gr) * K + gc;
  const unsigned short* agB = A  + (size_t)(bm + 64 + gr) * K + gc;
  const unsigned short* bgA = Bt + (size_t)(bn + gr) * K + gc;
  const unsigned short* bgB = Bt + (size_t)(bn + 64 + gr) * K + gc;
  unsigned short* lAs0 = As + wave * 512;          // wave-uniform LDS bases
  unsigned short* lAs1 = As + 2048 + wave * 512;
  unsigned short* lBs0 = Bs + wave * 512;
  unsigned short* lBs1 = Bs + 2048 + wave * 512;

  f32x4 acc[4][4];
#pragma unroll
  for (int mi = 0; mi < 4; ++mi)
#pragma unroll
    for (int ni = 0; ni < 4; ++ni) acc[mi][ni] = (f32x4){0.f, 0.f, 0.f, 0.f};

  for (int k0 = 0; k0 < K; k0 += 32) {
    GLOAD16(agA + k0, lAs0);
    GLOAD16(agB + k0, lAs1);
    GLOAD16(bgA + k0, lBs0);
    GLOAD16(bgB + k0, lBs1);
    __syncthreads();      // compiler drains vmcnt before barrier

    bf16x8 af[4], bf[4];
#pragma unroll
    for (int i = 0; i < 4; ++i) {
      af[i] = *(const bf16x8*)&As[(wm + i * 16 + n16) * 32 + quad * 8];
      bf[i] = *(const bf16x8*)&Bs[(wn + i * 16 + n16) * 32 + quad * 8];
    }
#pragma unroll
    for (int mi = 0; mi < 4; ++mi)
#pragma unroll
      for (int ni = 0; ni < 4; ++ni)
        acc[mi][ni] = __builtin_amdgcn_mfma_f32_16x16x32_bf16(af[mi], bf[ni], acc[mi][ni], 0, 0, 0);
    __syncthreads();
  }

#pragma unroll
  for (int mi = 0; mi < 4; ++mi) {
#pragma unroll
    for (int r = 0; r < 4; ++r) {
      const int row = bm + wm + mi * 16 + quad * 4 + r;
#pragma unroll
      for (int ni = 0; ni < 4; ++ni) {
        const int col = bn + wn + ni * 16 + n16;
        const float v = acc[mi][ni][r];
        if (REMAP == 0) {
          C[(size_t)row * N + col] = v;
        } else {
          const int b = row >> 11, t = row & (T_ - 1);
          const int part = col >> 9;
          const int kv = (col >> 7) & 3;
          const int hd = col & 127;
          C[(size_t)part * (B_ * KV_ * T_ * HD_) +
            (((size_t)(b * KV_ + kv) * T_) + t) * HD_ + hd] = v;
        }
      }
    }
  }
}

// ---------------- RoPE Q in place (f32 [BT, H*HD]) ----------------
__global__ __launch_bounds__(256) void rope_q(float* __restrict__ Q,
                                              const float* __restrict__ cosb,
                                              const float* __restrict__ sinb) {
  const int bt = blockIdx.x;
  const int t = bt % T_;
  const int tid = threadIdx.x;
  for (int i = tid; i < H_ * (RD_ / 2); i += 256) {
    const int h = i >> 5;
    const int p = i & 31;
    const float c = cosb[t * 32 + p];
    const float s = sinb[t * 32 + p];
    const size_t base = (size_t)bt * (H_ * HD_) + h * HD_ + 2 * p;
    const float e = Q[base], o = Q[base + 1];
    Q[base]     = e * c - o * s;
    Q[base + 1] = e * s + o * c;
  }
}

// ---------------- RoPE K in place (f32 [B,KV,T,HD]) + bf16 mirror ----------------
__global__ __launch_bounds__(256) void rope_k(float* __restrict__ kout,
                                              const float* __restrict__ cosb,
                                              const float* __restrict__ sinb,
                                              unsigned short* __restrict__ Kbf) {
  const int bt = blockIdx.x;
  const int t = bt % T_;
  const int b = bt / T_;
  const int tid = threadIdx.x;
  for (int i = tid; i < KV_ * (HD_ / 2); i += 256) {
    const int kv = i >> 6;
    const int p = i & 63;
    const size_t idx = (((size_t)(b * KV_ + kv) * T_) + t) * HD_ + 2 * p;
    float e = kout[idx], o = kout[idx + 1];
    if (p < 32) {
      const float c = cosb[t * 32 + p];
      const float s = sinb[t * 32 + p];
      const float re = e * c - o * s;
      const float ro = e * s + o * c;
      e = re; o = ro;
      kout[idx]     = e;
      kout[idx + 1] = o;
    }
    Kbf[idx]     = f2bu(e);
    Kbf[idx + 1] = f2bu(o);
  }
}

// ---------------- V transpose: vout f32 [G,T,HD] -> VbfT bf16 [G,HD,T], pi-permuted ----------------
// Within each 32-key chunk, keys are stored in the MFMA A-frag contraction order of the
// attention P fragment: slot(key k) = 8*(k%16/4) + (k<16 ? k%4 : 4 + k%4).
// Inverse (used here): 4 consecutive source keys kc..kc+3 land at slot base
// dstb = ((kc&15)<<1) | ((kc&16)>>2), contiguously.
__global__ __launch_bounds__(256) void v_transpose(const float* __restrict__ vin,
                                                   unsigned short* __restrict__ vt) {
  __shared__ unsigned int tile[32][17];
  const int tid = threadIdx.x;
  const int k0 = blockIdx.x * 32;
  const int d0 = blockIdx.y * 32;
  const int g  = blockIdx.z;
  const float* src = vin + ((size_t)g * T_ + k0) * HD_ + d0;

  {
    const int kr = tid >> 3;
    const int d2 = (tid & 7) * 2;
#pragma unroll
    for (int c = 0; c < 2; ++c) {
      const float2 f = *(const float2*)(src + (size_t)kr * HD_ + (d2 + c) * 2);
      tile[kr][d2 + c] = (unsigned)f2bu(f.x) | ((unsigned)f2bu(f.y) << 16);
    }
  }
  __syncthreads();
  {
    const int dr = tid >> 3;
    const int kc = (tid & 7) * 4;
    const int dstb = ((kc & 15) << 1) | ((kc & 16) >> 2);
    const int hi = dr >> 1;
    const int sh = (dr & 1) * 16;
    ushort4 o;
    o.x = (unsigned short)(tile[kc + 0][hi] >> sh);
    o.y = (unsigned short)(tile[kc + 1][hi] >> sh);
    o.z = (unsigned short)(tile[kc + 2][hi] >> sh);
    o.w = (unsigned short)(tile[kc + 3][hi] >> sh);
    *(ushort4*)(vt + ((size_t)g * HD_ + d0 + dr) * T_ + k0 + dstb) = o;
  }
}

// ---------------- flash attention v4: paired q-tiles, swapped QK^T, rescale-skip ----------------
// Block = (pair pid, b, kvh): tile A = qt pid, tile B = qt 127-pid -> nchA+nchB == 65 for
// every block (exact work balance; per-CU imbalance of v3 eliminated). 4 waves = 4 heads.
// Swapped QK^T (mfma(K,Q)) puts S rows lane-local: no S LDS round-trip; P's natural frag
// order is matched by the pi-permuted V layout (baked into v_transpose). K/V frag reads
// are shared between both tiles. Rescale-skip: when no row's max grows, alpha==1 exactly
// -> skip exp + LDS broadcast + 32-mul rescale (bit-identical math).
__global__ __launch_bounds__(256, 2) void attn_flash(const float* __restrict__ Q,
                                                     const unsigned short* __restrict__ Kbf,
                                                     const unsigned short* __restrict__ VbfT,
                                                     unsigned short* __restrict__ O) {
  __shared__ __align__(16) unsigned short Ks[32 * 128];  // [key][d], swizzled
  __shared__ __align__(16) unsigned short Vs[128 * 32];  // [d][key-slot], swizzled
  __shared__ __align__(16) float mBr[4][16];             // alpha broadcast, tile B
  __shared__ __align__(16) float mAr[4][16];             // alpha broadcast, tile A
  __shared__ __align__(16) float lBr[4][16];
  __shared__ __align__(16) float lAr[4][16];

  const int tid = threadIdx.x;
  const int wave = tid >> 6;        // = head within kv group
  const int lane = tid & 63;
  const int n16 = lane & 15;
  const int quad = lane >> 4;
  const int pid = blockIdx.x;       // 0..63
  const int q0A = pid * 16;
  const int q0B = (127 - pid) * 16;
  const int nchA = (q0A + 47) >> 5;
  const int nchB = (q0B + 47) >> 5;
  const int bkv = blockIdx.y;
  const int b = bkv >> 2;
  const int kvh = bkv & 3;
  const int h = kvh * 4 + wave;

  const unsigned short* ksrc = Kbf + ((size_t)(b * KV_ + kvh)) * T_ * HD_;
  const unsigned short* vtsrc = VbfT + ((size_t)(b * KV_ + kvh)) * HD_ * T_;

  // staging decomposition: 256 threads x 16B x 2 ops per tile
  const int krow = tid >> 4;            // 0..15 (+16 for second op)
  const int kcol = (tid & 15) * 8;
  const int kdst0 = (krow * 128 + kcol) ^ ((krow & 7) << 3);
  const int kdst1 = ((krow + 16) * 128 + kcol) ^ ((krow & 7) << 3);
  const int vrow = tid >> 2;            // 0..63 (+64 for second op)
  const int vcol = (tid & 3) * 8;
  const int vdst0 = (vrow * 32 + vcol) ^ ((vrow & 3) << 3);
  const int vdst1 = ((vrow + 64) * 32 + vcol) ^ ((vrow & 3) << 3);

  // Q A-frags for both tiles (scale folded in); lane n16 owns q-row q0+n16
  bf16x8 qfA[4], qfB[4];
  {
    const float* qa = Q + ((size_t)(b * T_ + q0A + n16)) * (H_ * HD_) + h * HD_ + quad * 8;
    const float* qb = Q + ((size_t)(b * T_ + q0B + n16)) * (H_ * HD_) + h * HD_ + quad * 8;
#pragma unroll
    for (int s = 0; s < 4; ++s) {
      union { bf16x8 v; unsigned short u[8]; } ta, tb;
#pragma unroll
      for (int j = 0; j < 8; ++j) {
        ta.u[j] = f2bu(qa[s * 32 + j] * SCALE_);
        tb.u[j] = f2bu(qb[s * 32 + j] * SCALE_);
      }
      qfA[s] = ta.v; qfB[s] = tb.v;
    }
  }

  float mA = -1e30f, lA = 0.f;
  float mB = -1e30f, lB = 0.f;
  f32x4 oA[8], oB[8];
#pragma unroll
  for (int t = 0; t < 8; ++t) { oA[t] = (f32x4){0.f,0.f,0.f,0.f}; oB[t] = (f32x4){0.f,0.f,0.f,0.f}; }

  // stage chunk 0
  {
    const u16x8 ka = *(const u16x8*)(ksrc + (size_t)krow * HD_ + kcol);
    const u16x8 kb = *(const u16x8*)(ksrc + (size_t)(krow + 16) * HD_ + kcol);
    const u16x8 va = *(const u16x8*)(vtsrc + (size_t)vrow * T_ + vcol);
    const u16x8 vb = *(const u16x8*)(vtsrc + (size_t)(vrow + 64) * T_ + vcol);
    *(u16x8*)&Ks[kdst0] = ka;
    *(u16x8*)&Ks[kdst1] = kb;
    *(u16x8*)&Vs[vdst0] = va;
    *(u16x8*)&Vs[vdst1] = vb;
  }
  __syncthreads();

  for (int c = 0; c < nchB; ++c) {
    const int kc = c * 32;
    const bool actA = (c < nchA);

    // prefetch next chunk to regs; LDS writes happen after the post-compute barrier
    u16x8 ka, kb, va, vb;
    if (c + 1 < nchB) {
      ka = *(const u16x8*)(ksrc + (size_t)(kc + 32 + krow) * HD_ + kcol);
      kb = *(const u16x8*)(ksrc + (size_t)(kc + 48 + krow) * HD_ + kcol);
      va = *(const u16x8*)(vtsrc + (size_t)vrow * T_ + (kc + 32) + vcol);
      vb = *(const u16x8*)(vtsrc + (size_t)(vrow + 64) * T_ + (kc + 32) + vcol);
    }
    COMPILER_BARRIER();

    // ---- swapped QK^T, K-frags shared by both tiles ----
    // acc[m=key(quad*4+r)][n=qrow(n16)]: lane holds S[kc+quad*4+r][q0+n16] (+16 in acc1)
    f32x4 sB0 = (f32x4){0.f,0.f,0.f,0.f}, sB1 = sB0, sA0 = sB0, sA1 = sB0;
#pragma unroll
    for (int s = 0; s < 4; ++s) {
      const bf16x8 kf0 = *(const bf16x8*)&Ks[(n16 * 128 + quad * 8 + s * 32) ^ ((n16 & 7) << 3)];
      const bf16x8 kf1 = *(const bf16x8*)&Ks[((16 + n16) * 128 + quad * 8 + s * 32) ^ ((n16 & 7) << 3)];
      sB0 = __builtin_amdgcn_mfma_f32_16x16x32_bf16(kf0, qfB[s], sB0, 0, 0, 0);
      sB1 = __builtin_amdgcn_mfma_f32_16x16x32_bf16(kf1, qfB[s], sB1, 0, 0, 0);
      if (actA) {
        sA0 = __builtin_amdgcn_mfma_f32_16x16x32_bf16(kf0, qfA[s], sA0, 0, 0, 0);
        sA1 = __builtin_amdgcn_mfma_f32_16x16x32_bf16(kf1, qfA[s], sA1, 0, 0, 0);
      }
    }

    // ---- softmax B (lane-local row q0B+n16; s[] is already in A-frag slot order) ----
    union { bf16x8 v; unsigned short u[8]; } pkB, pkA;
    bool growB;
    {
      float s[8];
#pragma unroll
      for (int r = 0; r < 4; ++r) { s[r] = sB0[r]; s[r + 4] = sB1[r]; }
      if (c == nchB - 1) {
        const int qrow = q0B + n16;
#pragma unroll
        for (int r = 0; r < 4; ++r) {
          if (kc + quad * 4 + r > qrow)      s[r]     = -1e30f;
          if (kc + 16 + quad * 4 + r > qrow) s[r + 4] = -1e30f;
        }
      }
      float mm = fmaxf(fmaxf(fmaxf(s[0], s[1]), fmaxf(s[2], s[3])),
                       fmaxf(fmaxf(s[4], s[5]), fmaxf(s[6], s[7])));
      mm = fmaxf(mm, __shfl_xor(mm, 16));
      mm = fmaxf(mm, __shfl_xor(mm, 32));
      growB = __any(mm > mB);
      float alpha = 1.f;
      if (growB) {
        const float mnew = fmaxf(mB, mm);
        alpha = __expf(mB - mnew);
        mB = mnew;
        if (quad == 0) mBr[wave][n16] = alpha;
      }
      float lsum = 0.f;
#pragma unroll
      for (int j = 0; j < 8; ++j) {
        const float p = __expf(s[j] - mB);
        lsum += p;
        pkB.u[j] = f2bu(p);
      }
      lsum += __shfl_xor(lsum, 16);
      lsum += __shfl_xor(lsum, 32);
      lB = growB ? (alpha * lB + lsum) : (lB + lsum);
    }

    // ---- softmax A ----
    bool growA = false;
    if (actA) {
      float s[8];
#pragma unroll
      for (int r = 0; r < 4; ++r) { s[r] = sA0[r]; s[r + 4] = sA1[r]; }
      if (c == nchA - 1) {
        const int qrow = q0A + n16;
#pragma unroll
        for (int r = 0; r < 4; ++r) {
          if (kc + quad * 4 + r > qrow)      s[r]     = -1e30f;
          if (kc + 16 + quad * 4 + r > qrow) s[r + 4] = -1e30f;
        }
      }
      float mm = fmaxf(fmaxf(fmaxf(s[0], s[1]), fmaxf(s[2], s[3])),
                       fmaxf(fmaxf(s[4], s[5]), fmaxf(s[6], s[7])));
      mm = fmaxf(mm, __shfl_xor(mm, 16));
      mm = fmaxf(mm, __shfl_xor(mm, 32));
      growA = __any(mm > mA);
      float alpha = 1.f;
      if (growA) {
        const float mnew = fmaxf(mA, mm);
        alpha = __expf(mA - mnew);
        mA = mnew;
        if (quad == 0) mAr[wave][n16] = alpha;
      }
      float lsum = 0.f;
#pragma unroll
      for (int j = 0; j < 8; ++j) {
        const float p = __expf(s[j] - mA);
        lsum += p;
        pkA.u[j] = f2bu(p);
      }
      lsum += __shfl_xor(lsum, 16);
      lsum += __shfl_xor(lsum, 32);
      lA = growA ? (alpha * lA + lsum) : (lA + lsum);
    }

    // ---- O rescale only when max grew (alpha==1 exact skip otherwise) ----
    if (growB) {
      COMPILER_BARRIER();   // same-wave in-order DS: mBr write before read
      const f32x4 av = *(const f32x4*)&mBr[wave][quad * 4];
#pragma unroll
      for (int t = 0; t < 8; ++t) {
        oB[t][0] *= av[0]; oB[t][1] *= av[1]; oB[t][2] *= av[2]; oB[t][3] *= av[3];
      }
    }
    if (growA) {
      COMPILER_BARRIER();
      const f32x4 av = *(const f32x4*)&mAr[wave][quad * 4];
#pragma unroll
      for (int t = 0; t < 8; ++t) {
        oA[t][0] *= av[0]; oA[t][1] *= av[1]; oA[t][2] *= av[2]; oA[t][3] *= av[3];
      }
    }

    // ---- PV, V-frags shared by both tiles (pi-permuted layout matches pk order) ----
#pragma unroll
    for (int t = 0; t < 8; ++t) {
      const bf16x8 vf = *(const bf16x8*)&Vs[((t * 16 + n16) * 32 + quad * 8) ^ ((n16 & 3) << 3)];
      oB[t] = __builtin_amdgcn_mfma_f32_16x16x32_bf16(pkB.v, vf, oB[t], 0, 0, 0);
      if (actA) oA[t] = __builtin_amdgcn_mfma_f32_16x16x32_bf16(pkA.v, vf, oA[t], 0, 0, 0);
    }

    __syncthreads();      // all waves done reading this chunk's K/V tiles
    if (c + 1 < nchB) {
      *(u16x8*)&Ks[kdst0] = ka;
      *(u16x8*)&Ks[kdst1] = kb;
      *(u16x8*)&Vs[vdst0] = va;
      *(u16x8*)&Vs[vdst1] = vb;
    }
    __syncthreads();      // next chunk's tiles visible to all waves
  }

  // ---- epilogue: l -> C-layout via LDS, normalize, store bf16 (both tiles) ----
  if (quad == 0) { lBr[wave][n16] = lB; lAr[wave][n16] = lA; }
  COMPILER_BARRIER();
  {
    const f32x4 lBC = *(const f32x4*)&lBr[wave][quad * 4];
    const f32x4 lAC = *(const f32x4*)&lAr[wave][quad * 4];
    unsigned short* obB = O + ((size_t)(b * T_ + q0B)) * (H_ * HD_) + h * HD_;
    unsigned short* obA = O + ((size_t)(b * T_ + q0A)) * (H_ * HD_) + h * HD_;
#pragma unroll
    for (int r = 0; r < 4; ++r) {
      const float liB = 1.0f / lBC[r];
      const float liA = 1.0f / lAC[r];
#pragma unroll
      for (int t = 0; t < 8; ++t) {
        obB[(size_t)(quad * 4 + r) * (H_ * HD_) + t * 16 + n16] = f2bu(oB[t][r] * liB);
        obA[(size_t)(quad * 4 + r) * (H_ * HD_) + t * 16 + n16] = f2bu(oA[t][r] * liA);
      }
    }
  }
}

extern "C" void kernel_launch(void* const* d_in, const int* in_sizes, int n_in,
                              void* d_out, int out_size, void* d_ws, size_t ws_size,
                              hipStream_t stream) {
  const float* x  = (const float*)d_in[0];
  const float* fc = (const float*)d_in[1];
  const float* fs = (const float*)d_in[2];
  const float* Wq = (const float*)d_in[3];
  const float* Wk = (const float*)d_in[4];
  const float* Wv = (const float*)d_in[5];
  const float* Wo = (const float*)d_in[6];

  // Outputs (f32), concatenated: y | present_k | present_v
  float* yout = (float*)d_out;                          // [B,T,D]
  float* kout = yout + (size_t)B_ * T_ * D_;            // [B,KV,T,HD]
  float* vout = kout + (size_t)B_ * KV_ * T_ * HD_;     // [B,KV,T,HD]
  float* Qb = yout;                                     // f32 Q staging in yout region

  // workspace (bf16, 46.1 MB): xb/Abf (aliased) | Wqt | Wkvt | Wot | Kbf | VbfT
  unsigned short* xb   = (unsigned short*)d_ws;                    // [BT, D]
  unsigned short* Abf  = xb;                                       // alias: xb dead after projections
  unsigned short* Wqt  = xb   + (size_t)BT_ * D_;                  // [2048, 2048]
  unsigned short* Wkvt = Wqt  + (size_t)D_ * D_;                   // [1024, 2048]
  unsigned short* Wot  = Wkvt + (size_t)1024 * D_;                 // [2048, 2048]
  unsigned short* Kbf  = Wot  + (size_t)D_ * D_;                   // [B,KV,T,HD]
  unsigned short* VbfT = Kbf  + (size_t)B_ * KV_ * T_ * HD_;       // [B*KV, HD, T] (pi-permuted)

  dim3 blk(256);

  // input conversions
  cvt_bf16<<<dim3((BT_ * D_) / 1024), blk, 0, stream>>>(x, xb);
  t32<<<dim3(D_ / 32, D_ / 32), blk, 0, stream>>>(Wq, Wqt, D_, D_);
  t32<<<dim3(D_ / 32, 512 / 32), blk, 0, stream>>>(Wk, Wkvt, D_, 512);
  t32<<<dim3(D_ / 32, 512 / 32), blk, 0, stream>>>(Wv, Wkvt + (size_t)512 * D_, D_, 512);
  t32<<<dim3(D_ / 32, D_ / 32), blk, 0, stream>>>(Wo, Wot, D_, D_);

  // projections (bf16 MFMA, f32 out)
  gemm_bf16<0><<<dim3(D_ / 128, BT_ / 128), blk, 0, stream>>>(xb, Wqt, Qb, BT_, D_, D_);
  gemm_bf16<1><<<dim3(1024 / 128, BT_ / 128), blk, 0, stream>>>(xb, Wkvt, kout, BT_, 1024, D_);

  // RoPE (Q and K in place) + bf16 K mirror; V^T bf16 mirror (pi-permuted)
  rope_q<<<dim3(BT_), blk, 0, stream>>>(Qb, fc, fs);
  rope_k<<<dim3(BT_), blk, 0, stream>>>(kout, fc, fs, Kbf);
  v_transpose<<<dim3(T_ / 32, HD_ / 32, B_ * KV_), blk, 0, stream>>>(vout, VbfT);

  // flash attention v4: 512 equal-work paired blocks, 4 waves each
  attn_flash<<<dim3(64, B_ * KV_), dim3(256), 0, stream>>>(Qb, Kbf, VbfT, Abf);

  // output projection; overwrites Qb staging with y
  gemm_bf16<0><<<dim3(D_ / 128, BT_ / 128), blk, 0, stream>>>(Abf, Wot, yout, BT_, D_, D_);
}